// Round 1
// baseline (9930.585 us; speedup 1.0000x reference)
//
#include <hip/hip_runtime.h>
#include <math.h>

#define NNODE 65536
#define NBAT  16384   // nodes per batch (128*128)
#define HID   128
#define NP    5
#define DT    0.1f
#define EPS   1e-5f

__device__ __forceinline__ float swishf(float x) {
    return x / (1.f + __expf(-x));
}

// ---------------- node scalars: u, pos, 1/deg ----------------
__global__ __launch_bounds__(256) void node_init(
    const float* __restrict__ inp, const float* __restrict__ cp,
    float* __restrict__ u, float* __restrict__ posx, float* __restrict__ posy,
    float* __restrict__ invd)
{
    int n = blockIdx.x * 256 + threadIdx.x;
    int b = n >> 14, r = n & 16383;
    int a = r >> 7, c = r & 127;
    u[n] = inp[b * 3 * NBAT + r];          // channel 0 of (B,C,H,W)
    posx[n] = (a * (1.f / 127.f)) * cp[b * NP + 1];
    posy[n] = (c * (1.f / 127.f)) * cp[b * NP + 0];
    int ca = 1 + (a > 0) + (a < 127);
    int cc = 1 + (c > 0) + (c < 127);
    invd[n] = 1.f / (float)(ca * cc - 1);
}

// ---------------- embedding MLP: 8 -> 128 -> 128 ----------------
__global__ __launch_bounds__(256) void embed_kernel(
    const float* __restrict__ u, const float* __restrict__ posx,
    const float* __restrict__ posy, const float* __restrict__ cp,
    const float* __restrict__ W1, const float* __restrict__ b1,
    const float* __restrict__ W2, const float* __restrict__ b2,
    float* __restrict__ f)
{
    __shared__ float hid[2][128];
    int o = threadIdx.x & 127, j = threadIdx.x >> 7;
    int n = blockIdx.x * 2 + j;
    int b = n >> 14;
    float e[8];
    e[0] = u[n]; e[1] = posx[n]; e[2] = posy[n];
#pragma unroll
    for (int p = 0; p < 5; p++) e[3 + p] = cp[b * NP + p];
    float acc = b1[o];
#pragma unroll
    for (int k = 0; k < 8; k++) acc += e[k] * W1[k * 128 + o];
    hid[j][o] = swishf(acc);
    __syncthreads();
    float acc2 = b2[o];
#pragma unroll 4
    for (int k = 0; k < 128; k++) acc2 += hid[j][k] * W2[k * 128 + o];
    f[n * 128 + o] = swishf(acc2);
}

// ---------------- per-node Pn/Qn (factorized msg1) ----------------
// Pn[t] = f[t]@W[0:128] + u*W[256] + posx*W[257] + posy*W[258] + params@W[259:264] + b1
// Qn[s] = f[s]@W[128:256] - u*W[256] - posx*W[257] - posy*W[258]
__global__ __launch_bounds__(256) void pq_kernel(
    const float* __restrict__ f, const float* __restrict__ u,
    const float* __restrict__ posx, const float* __restrict__ posy,
    const float* __restrict__ cp,
    const float* __restrict__ mW, const float* __restrict__ mb,
    float* __restrict__ Pn, float* __restrict__ Qn)
{
    __shared__ float fr[2][128];
    int o = threadIdx.x & 127, j = threadIdx.x >> 7;
    int n = blockIdx.x * 2 + j;
    int b = n >> 14;
    fr[j][o] = f[n * 128 + o];
    __syncthreads();
    float p = mb[o], q = 0.f;
#pragma unroll 4
    for (int k = 0; k < 128; k++) {
        float fv = fr[j][k];
        p += fv * mW[k * 128 + o];
        q += fv * mW[(128 + k) * 128 + o];
    }
    float uu = u[n], px = posx[n], py = posy[n];
    float wu = mW[256 * 128 + o], wx = mW[257 * 128 + o], wy = mW[258 * 128 + o];
    float sc = uu * wu + px * wx + py * wy;
    p += sc; q -= sc;
#pragma unroll
    for (int t = 0; t < 5; t++) p += cp[b * NP + t] * mW[(259 + t) * 128 + o];
    Pn[n * 128 + o] = p;
    Qn[n * 128 + o] = q;
}

// ---------------- per-target message MLP stage 2 + aggregation ----------------
// one block per target node; 8 edges in parallel (32 lanes x 4 outputs each)
__global__ __launch_bounds__(256) void msg_agg(
    const float* __restrict__ Pn, const float* __restrict__ Qn,
    const float* __restrict__ W2, const float* __restrict__ b2,
    const float* __restrict__ invd, float* __restrict__ agg)
{
    __shared__ __align__(16) float hid[8][128];
    __shared__ __align__(16) float pnt[128];
    int t = blockIdx.x;
    int b = t >> 14, r = t & 16383;
    int a = r >> 7, c = r & 127;
    int tid = threadIdx.x;
    int e = tid >> 5;       // edge slot 0..7
    int og = tid & 31;      // output group (4 outputs)

    // neighbor for edge slot e:  3x3 minus center
    int idx = (e < 4) ? e : (e + 1);
    int dx = idx / 3 - 1, dy = idx % 3 - 1;
    int na = a + dx, nc = c + dy;
    bool valid = (na >= 0) & (na < 128) & (nc >= 0) & (nc < 128);
    int s = valid ? (b * NBAT + na * 128 + nc) : t;

    if (tid < 32) ((float4*)pnt)[tid] = ((const float4*)(Pn + (size_t)t * 128))[tid];
    __syncthreads();

    // hidden = swish(Pn[t] + Qn[s]); zero for invalid edges handled at mask below
    float4 qv = ((const float4*)(Qn + (size_t)s * 128))[og];
    float4 pv = ((const float4*)pnt)[og];
    float4 h;
    h.x = swishf(pv.x + qv.x);
    h.y = swishf(pv.y + qv.y);
    h.z = swishf(pv.z + qv.z);
    h.w = swishf(pv.w + qv.w);
    ((float4*)&hid[e][0])[og] = h;
    __syncthreads();

    // m[e][4og..4og+3] = swish(hidden[e] @ W2 + b2)
    float a0 = 0.f, a1 = 0.f, a2 = 0.f, a3 = 0.f;
    const float* hrow = hid[e];
#pragma unroll 4
    for (int k = 0; k < 128; k++) {
        float hv = hrow[k];
        float4 w = ((const float4*)(W2 + k * 128))[og];
        a0 += hv * w.x; a1 += hv * w.y; a2 += hv * w.z; a3 += hv * w.w;
    }
    float4 bb = ((const float4*)b2)[og];
    float4 m;
    m.x = valid ? swishf(a0 + bb.x) : 0.f;
    m.y = valid ? swishf(a1 + bb.y) : 0.f;
    m.z = valid ? swishf(a2 + bb.z) : 0.f;
    m.w = valid ? swishf(a3 + bb.w) : 0.f;
    __syncthreads();                       // everyone done reading hid
    ((float4*)&hid[e][0])[og] = m;         // reuse hid as m buffer
    __syncthreads();

    if (tid < 128) {
        float sacc = 0.f;
#pragma unroll
        for (int ee = 0; ee < 8; ee++) sacc += hid[ee][tid];
        agg[(size_t)t * 128 + tid] = sacc * invd[t];
    }
}

// ---------------- node update MLP: [f, agg, params] -> 128 -> 128, residual ----------------
__global__ __launch_bounds__(256) void update_kernel(
    float* __restrict__ f, const float* __restrict__ agg, const float* __restrict__ cp,
    const float* __restrict__ U1, const float* __restrict__ c1,
    const float* __restrict__ U2, const float* __restrict__ c2)
{
    __shared__ float fa[2][256];
    __shared__ float hid[2][128];
    int o = threadIdx.x & 127, j = threadIdx.x >> 7;
    int n = blockIdx.x * 2 + j;
    int b = n >> 14;
    fa[j][o] = f[n * 128 + o];
    fa[j][128 + o] = agg[n * 128 + o];
    __syncthreads();
    float acc = c1[o];
#pragma unroll 4
    for (int k = 0; k < 256; k++) acc += fa[j][k] * U1[k * 128 + o];
#pragma unroll
    for (int p = 0; p < 5; p++) acc += cp[b * NP + p] * U1[(256 + p) * 128 + o];
    hid[j][o] = swishf(acc);
    __syncthreads();
    float acc2 = c2[o];
#pragma unroll 4
    for (int k = 0; k < 128; k++) acc2 += hid[j][k] * U2[k * 128 + o];
    f[n * 128 + o] = fa[j][o] + swishf(acc2);
}

// ---------------- per-batch, per-channel stats (sum, sumsq) ----------------
__global__ __launch_bounds__(256) void stats_kernel(
    const float* __restrict__ f, float* __restrict__ stats)
{
    __shared__ float redA[256], redB[256];
    int blk = blockIdx.x;
    int b = blk >> 6;          // 64 slices per batch
    int slice = blk & 63;
    int base = b * NBAT + slice * 256;
    int tid = threadIdx.x;
    int ch = tid & 127, half = tid >> 7;
    float s = 0.f, s2 = 0.f;
    for (int rr = half; rr < 256; rr += 2) {
        float v = f[(size_t)(base + rr) * 128 + ch];
        s += v; s2 += v * v;
    }
    redA[tid] = s; redB[tid] = s2;
    __syncthreads();
    if (tid < 128) {
        s = redA[tid] + redA[tid + 128];
        s2 = redB[tid] + redB[tid + 128];
        atomicAdd(&stats[b * 256 + tid], s);
        atomicAdd(&stats[b * 256 + 128 + tid], s2);
    }
}

// ---------------- apply normalization ----------------
__global__ __launch_bounds__(256) void norm_apply(
    const float* __restrict__ stats, float* __restrict__ f)
{
    int idx = blockIdx.x * 256 + threadIdx.x;   // over NNODE*128
    int ch = idx & 127;
    int n = idx >> 7;
    int b = n >> 14;
    float mean = stats[b * 256 + ch] * (1.f / 16384.f);
    float ex2  = stats[b * 256 + 128 + ch] * (1.f / 16384.f);
    float var = ex2 - mean * mean;
    f[idx] = (f[idx] - mean) * rsqrtf(var + EPS);
}

// ---------------- output head: 128 -> 64 -> 1, out = u + DT*diff ----------------
__global__ __launch_bounds__(256) void out_head(
    const float* __restrict__ f, const float* __restrict__ u,
    const float* __restrict__ O1, const float* __restrict__ ob1,
    const float* __restrict__ O2, const float* __restrict__ ob2,
    float* __restrict__ out)
{
    __shared__ float fr[4][128];
    int tid = threadIdx.x;
    int w = tid >> 6, lane = tid & 63;
    int n = blockIdx.x * 4 + w;
    fr[w][lane] = f[(size_t)n * 128 + lane];
    fr[w][64 + lane] = f[(size_t)n * 128 + 64 + lane];
    __syncthreads();
    float acc = ob1[lane];
#pragma unroll 4
    for (int k = 0; k < 128; k++) acc += fr[w][k] * O1[k * 64 + lane];
    float v = swishf(acc) * O2[lane];
#pragma unroll
    for (int off = 32; off > 0; off >>= 1) v += __shfl_down(v, off);
    if (lane == 0) out[n] = u[n] + DT * (v + ob2[0]);
}

extern "C" void kernel_launch(void* const* d_in, const int* in_sizes, int n_in,
                              void* d_out, int out_size, void* d_ws, size_t ws_size,
                              hipStream_t stream)
{
    const float* inputs = (const float*)d_in[0];
    const float* cp     = (const float*)d_in[1];
    // d_in[2] = edge_index (int32) — connectivity regenerated arithmetically
    const float* emb_W1 = (const float*)d_in[3];
    const float* emb_b1 = (const float*)d_in[4];
    const float* emb_W2 = (const float*)d_in[5];
    const float* emb_b2 = (const float*)d_in[6];
    const float* msg1_W = (const float*)d_in[7];
    const float* msg1_b = (const float*)d_in[8];
    const float* msg2_W = (const float*)d_in[9];
    const float* msg2_b = (const float*)d_in[10];
    const float* upd1_W = (const float*)d_in[11];
    const float* upd1_b = (const float*)d_in[12];
    const float* upd2_W = (const float*)d_in[13];
    const float* upd2_b = (const float*)d_in[14];
    const float* out_W1 = (const float*)d_in[15];
    const float* out_b1 = (const float*)d_in[16];
    const float* out_W2 = (const float*)d_in[17];
    const float* out_b2 = (const float*)d_in[18];
    float* out = (float*)d_out;

    float* ws   = (float*)d_ws;
    float* f    = ws;                    // 65536*128
    float* Pn   = ws + 8388608;          // 65536*128
    float* Qn   = ws + 16777216;         // 65536*128
    float* agg  = ws + 25165824;         // 65536*128
    float* u    = ws + 33554432;         // 65536
    float* posx = u + 65536;
    float* posy = posx + 65536;
    float* invd = posy + 65536;
    float* stats = invd + 65536;         // 4*256

    node_init<<<256, 256, 0, stream>>>(inputs, cp, u, posx, posy, invd);
    embed_kernel<<<32768, 256, 0, stream>>>(u, posx, posy, cp,
                                            emb_W1, emb_b1, emb_W2, emb_b2, f);
    for (int l = 0; l < 6; l++) {
        pq_kernel<<<32768, 256, 0, stream>>>(f, u, posx, posy, cp,
                                             msg1_W + (size_t)l * 264 * 128,
                                             msg1_b + (size_t)l * 128, Pn, Qn);
        msg_agg<<<65536, 256, 0, stream>>>(Pn, Qn,
                                           msg2_W + (size_t)l * 128 * 128,
                                           msg2_b + (size_t)l * 128, invd, agg);
        update_kernel<<<32768, 256, 0, stream>>>(f, agg, cp,
                                                 upd1_W + (size_t)l * 261 * 128,
                                                 upd1_b + (size_t)l * 128,
                                                 upd2_W + (size_t)l * 128 * 128,
                                                 upd2_b + (size_t)l * 128);
        hipMemsetAsync(stats, 0, 1024 * sizeof(float), stream);
        stats_kernel<<<256, 256, 0, stream>>>(f, stats);
        norm_apply<<<32768, 256, 0, stream>>>(stats, f);
    }
    out_head<<<16384, 256, 0, stream>>>(f, u, out_W1, out_b1, out_W2, out_b2, out);
}

// Round 2
// 1799.804 us; speedup vs baseline: 5.5176x; 5.5176x over previous
//
#include <hip/hip_runtime.h>
#include <math.h>

#define NNODE 65536
#define NBAT  16384
#define HID   128
#define NP    5
#define DT    0.1f
#define EPS   1e-5f
#define LDK   136   // padded LDS K-stride (bf16 elems) for 128-wide rows

typedef __attribute__((ext_vector_type(8))) short short8;
typedef __attribute__((ext_vector_type(4))) float floatx4;

__device__ __forceinline__ float swishf(float x) {
    return x / (1.f + __expf(-x));
}
__device__ __forceinline__ float b2f(unsigned short v) {
    union { unsigned int u; float f; } x; x.u = ((unsigned int)v) << 16; return x.f;
}
__device__ __forceinline__ unsigned short f2b(float f) {
    union { float f; unsigned int u; } x; x.f = f;
    unsigned int r = x.u + 0x7fff + ((x.u >> 16) & 1);
    return (unsigned short)(r >> 16);
}

// ---------------- weight prep: fp32 [L][rows][128] -> bf16 [L][128][kout] (transposed) ----
__global__ __launch_bounds__(256) void prep_w(
    const float* __restrict__ src, unsigned short* __restrict__ dst,
    int rows, int koff, int kout, int total)
{
    int i = blockIdx.x * 256 + threadIdx.x;
    if (i >= total) return;
    int k = i % kout;
    int n = (i / kout) & 127;
    int l = i / (kout * 128);
    dst[i] = f2b(src[((size_t)l * rows + koff + k) * 128 + n]);
}

// ---------------- node scalars ----------------
__global__ __launch_bounds__(256) void node_init(
    const float* __restrict__ inp, const float* __restrict__ cp,
    float* __restrict__ u, float* __restrict__ posx, float* __restrict__ posy)
{
    int n = blockIdx.x * 256 + threadIdx.x;
    int b = n >> 14, r = n & 16383;
    int a = r >> 7, c = r & 127;
    u[n] = inp[b * 3 * NBAT + r];
    posx[n] = (a * (1.f / 127.f)) * cp[b * NP + 1];
    posy[n] = (c * (1.f / 127.f)) * cp[b * NP + 0];
}

// ---------------- embedding MLP: 8 -> 128 -> 128 (fp32, small) ----------------
__global__ __launch_bounds__(256) void embed_kernel(
    const float* __restrict__ u, const float* __restrict__ posx,
    const float* __restrict__ posy, const float* __restrict__ cp,
    const float* __restrict__ W1, const float* __restrict__ b1,
    const float* __restrict__ W2, const float* __restrict__ b2,
    float* __restrict__ f, unsigned short* __restrict__ fbf)
{
    __shared__ float hid[2][128];
    int o = threadIdx.x & 127, j = threadIdx.x >> 7;
    int n = blockIdx.x * 2 + j;
    int b = n >> 14;
    float e[8];
    e[0] = u[n]; e[1] = posx[n]; e[2] = posy[n];
#pragma unroll
    for (int p = 0; p < 5; p++) e[3 + p] = cp[b * NP + p];
    float acc = b1[o];
#pragma unroll
    for (int k = 0; k < 8; k++) acc += e[k] * W1[k * 128 + o];
    hid[j][o] = swishf(acc);
    __syncthreads();
    float acc2 = b2[o];
#pragma unroll 4
    for (int k = 0; k < 128; k++) acc2 += hid[j][k] * W2[k * 128 + o];
    float v = swishf(acc2);
    f[n * 128 + o] = v;
    fbf[n * 128 + o] = f2b(v);
}

// ---------------- pq: Pn/Qn = f @ {W_P, W_Q} + scalar terms (MFMA) ----------------
__global__ __launch_bounds__(256) void pq_mfma(
    const unsigned short* __restrict__ fbf,
    const unsigned short* __restrict__ wPT,   // [128][128] bf16 (n-major)
    const unsigned short* __restrict__ wQT,
    const float* __restrict__ mW,             // fp32 [264][128] layer slice
    const float* __restrict__ mb,
    const float* __restrict__ u, const float* __restrict__ px,
    const float* __restrict__ py, const float* __restrict__ cp,
    unsigned short* __restrict__ Pn, unsigned short* __restrict__ Qn)
{
    __shared__ unsigned short lA[64 * LDK];
    __shared__ unsigned short lB[128 * LDK];
    int tid = threadIdx.x;
    int block0 = blockIdx.x * 64;
    int b = block0 >> 14;

    // load A tile: 64 rows x 128 bf16
    {
        int r = tid >> 2, p4 = tid & 3;
        const unsigned short* src = fbf + (size_t)(block0 + r) * 128 + p4 * 32;
        unsigned short* dst = lA + r * LDK + p4 * 32;
#pragma unroll
        for (int j = 0; j < 4; j++)
            *(short8*)(dst + j * 8) = *(const short8*)(src + j * 8);
    }

    int w = tid >> 6, lane = tid & 63;
    int lm = lane & 15, lq = lane >> 4;

    float u4[4], px4[4], py4[4];
#pragma unroll
    for (int r = 0; r < 4; r++) {
        int nd = block0 + w * 16 + lq * 4 + r;
        u4[r] = u[nd]; px4[r] = px[nd]; py4[r] = py[nd];
    }
    float cp5[5];
#pragma unroll
    for (int p = 0; p < 5; p++) cp5[p] = cp[b * NP + p];

    for (int half = 0; half < 2; half++) {
        const unsigned short* wT = half ? wQT : wPT;
        __syncthreads();
        {
            int r = tid >> 1, p4 = tid & 1;
            const unsigned short* src = wT + r * 128 + p4 * 64;
            unsigned short* dst = lB + r * LDK + p4 * 64;
#pragma unroll
            for (int j = 0; j < 8; j++)
                *(short8*)(dst + j * 8) = *(const short8*)(src + j * 8);
        }
        __syncthreads();

        floatx4 acc[8];
#pragma unroll
        for (int t = 0; t < 8; t++) acc[t] = (floatx4)(0.f);
#pragma unroll
        for (int ks = 0; ks < 4; ks++) {
            short8 a = *(const short8*)(lA + (w * 16 + lm) * LDK + ks * 32 + lq * 8);
#pragma unroll
            for (int t = 0; t < 8; t++) {
                short8 bf = *(const short8*)(lB + (t * 16 + lm) * LDK + ks * 32 + lq * 8);
                acc[t] = __builtin_amdgcn_mfma_f32_16x16x32_bf16(a, bf, acc[t], 0, 0, 0);
            }
        }
        // epilogue
#pragma unroll
        for (int t = 0; t < 8; t++) {
            int col = t * 16 + lm;
            float wu = mW[256 * 128 + col], wx = mW[257 * 128 + col], wy = mW[258 * 128 + col];
            if (half == 0) {
                float pt = mb[col];
#pragma unroll
                for (int p = 0; p < 5; p++) pt += cp5[p] * mW[(259 + p) * 128 + col];
#pragma unroll
                for (int r = 0; r < 4; r++) {
                    int nd = block0 + w * 16 + lq * 4 + r;
                    float v = acc[t][r] + pt + u4[r] * wu + px4[r] * wx + py4[r] * wy;
                    Pn[(size_t)nd * 128 + col] = f2b(v);
                }
            } else {
#pragma unroll
                for (int r = 0; r < 4; r++) {
                    int nd = block0 + w * 16 + lq * 4 + r;
                    float v = acc[t][r] - (u4[r] * wu + px4[r] * wx + py4[r] * wy);
                    Qn[(size_t)nd * 128 + col] = f2b(v);
                }
            }
        }
    }
}

// ---------------- msg: hidden=swish(P[t]+Q[s]); m=swish(hidden@W2+b2); agg (MFMA) ----
__global__ __launch_bounds__(256) void msg_mfma(
    const unsigned short* __restrict__ Pn,
    const unsigned short* __restrict__ Qn,
    const unsigned short* __restrict__ w2T,
    const float* __restrict__ b2,
    unsigned short* __restrict__ agg)
{
    __shared__ unsigned short lH[64 * LDK];
    __shared__ unsigned short lB[128 * LDK];
    __shared__ unsigned short lAgg[8 * 128];
    int tid = threadIdx.x;
    int base = blockIdx.x * 8;            // 8 targets (same grid row)
    int b = base >> 14;
    int a = (base >> 7) & 127;
    int c0 = base & 127;

    // phase 1: build 64 hidden rows (8 targets x 8 edges)
    {
        int row = tid >> 2, p4 = tid & 3;
        int tl = row >> 3, e = row & 7;
        int idx = (e < 4) ? e : e + 1;
        int dx = idx / 3 - 1, dy = idx % 3 - 1;
        int na = a + dx, nc = c0 + tl + dy;
        bool valid = (na >= 0) & (na < 128) & (nc >= 0) & (nc < 128);
        int t = base + tl;
        int s = valid ? ((b << 14) + (na << 7) + nc) : t;
        const unsigned short* Prow = Pn + (size_t)t * 128 + p4 * 32;
        const unsigned short* Qrow = Qn + (size_t)s * 128 + p4 * 32;
        unsigned short* dst = lH + row * LDK + p4 * 32;
#pragma unroll
        for (int j = 0; j < 4; j++) {
            short8 pv = *(const short8*)(Prow + j * 8);
            short8 qv = *(const short8*)(Qrow + j * 8);
            short8 hh;
#pragma unroll
            for (int k = 0; k < 8; k++)
                hh[k] = (short)f2b(swishf(b2f((unsigned short)pv[k]) + b2f((unsigned short)qv[k])));
            *(short8*)(dst + j * 8) = hh;
        }
    }
    // load W2^T
    {
        int r = tid >> 1, p4 = tid & 1;
        const unsigned short* src = w2T + r * 128 + p4 * 64;
        unsigned short* dst = lB + r * LDK + p4 * 64;
#pragma unroll
        for (int j = 0; j < 8; j++)
            *(short8*)(dst + j * 8) = *(const short8*)(src + j * 8);
    }
    __syncthreads();

    int w = tid >> 6, lane = tid & 63;
    int lm = lane & 15, lq = lane >> 4;

    floatx4 acc[8];
#pragma unroll
    for (int t = 0; t < 8; t++) acc[t] = (floatx4)(0.f);
#pragma unroll
    for (int ks = 0; ks < 4; ks++) {
        short8 af = *(const short8*)(lH + (w * 16 + lm) * LDK + ks * 32 + lq * 8);
#pragma unroll
        for (int t = 0; t < 8; t++) {
            short8 bf = *(const short8*)(lB + (t * 16 + lm) * LDK + ks * 32 + lq * 8);
            acc[t] = __builtin_amdgcn_mfma_f32_16x16x32_bf16(af, bf, acc[t], 0, 0, 0);
        }
    }

    // epilogue: m = valid ? swish(acc + b2) : 0 ; reduce over 8 edges; * 1/deg
#pragma unroll
    for (int t = 0; t < 8; t++) {
        int col = t * 16 + lm;
        float bb = b2[col];
        float s01 = 0.f;
#pragma unroll
        for (int r = 0; r < 4; r++) {
            int row = lq * 4 + r;          // 0..15 in wave tile
            int tl2 = row >> 3;            // 0/1
            int e = row & 7;
            int tl = w * 2 + tl2;
            int cc = c0 + tl;
            int idx = (e < 4) ? e : e + 1;
            int dx = idx / 3 - 1, dy = idx % 3 - 1;
            int na = a + dx, nc = cc + dy;
            bool valid = (na >= 0) & (na < 128) & (nc >= 0) & (nc < 128);
            float m = valid ? swishf(acc[t][r] + bb) : 0.f;
            s01 += m;
        }
        float o = s01 + __shfl_xor(s01, 16);
        if ((lq & 1) == 0) {               // lq 0 -> target 2w, lq 2 -> target 2w+1
            int tl = w * 2 + (lq >> 1);
            int cc = c0 + tl;
            int deg = (1 + (a > 0) + (a < 127)) * (1 + (cc > 0) + (cc < 127)) - 1;
            lAgg[tl * 128 + col] = f2b(o / (float)deg);
        }
    }
    __syncthreads();
    if (tid < 128)
        *(short8*)(agg + (size_t)base * 128 + tid * 8) = *(const short8*)(lAgg + tid * 8);
}

// ---------------- update stage 1: hid = swish([f,agg]@U1 + params + c1) (MFMA) ----------
__global__ __launch_bounds__(256) void upd1_mfma(
    const unsigned short* __restrict__ fbf,
    const unsigned short* __restrict__ aggb,
    const unsigned short* __restrict__ u1T,   // [128][256] bf16
    const float* __restrict__ U1,             // fp32 [261][128] layer slice
    const float* __restrict__ c1, const float* __restrict__ cp,
    unsigned short* __restrict__ hid)
{
    __shared__ unsigned short lA[64 * LDK];
    __shared__ unsigned short lB[128 * LDK];
    int tid = threadIdx.x;
    int block0 = blockIdx.x * 64;
    int b = block0 >> 14;
    int w = tid >> 6, lane = tid & 63;
    int lm = lane & 15, lq = lane >> 4;

    floatx4 acc[8];
#pragma unroll
    for (int t = 0; t < 8; t++) acc[t] = (floatx4)(0.f);

    for (int half = 0; half < 2; half++) {
        const unsigned short* asrc = half ? aggb : fbf;
        __syncthreads();
        {
            int r = tid >> 2, p4 = tid & 3;
            const unsigned short* src = asrc + (size_t)(block0 + r) * 128 + p4 * 32;
            unsigned short* dst = lA + r * LDK + p4 * 32;
#pragma unroll
            for (int j = 0; j < 4; j++)
                *(short8*)(dst + j * 8) = *(const short8*)(src + j * 8);
        }
        {
            int r = tid >> 1, p4 = tid & 1;
            const unsigned short* src = u1T + r * 256 + half * 128 + p4 * 64;
            unsigned short* dst = lB + r * LDK + p4 * 64;
#pragma unroll
            for (int j = 0; j < 8; j++)
                *(short8*)(dst + j * 8) = *(const short8*)(src + j * 8);
        }
        __syncthreads();
#pragma unroll
        for (int ks = 0; ks < 4; ks++) {
            short8 a = *(const short8*)(lA + (w * 16 + lm) * LDK + ks * 32 + lq * 8);
#pragma unroll
            for (int t = 0; t < 8; t++) {
                short8 bf = *(const short8*)(lB + (t * 16 + lm) * LDK + ks * 32 + lq * 8);
                acc[t] = __builtin_amdgcn_mfma_f32_16x16x32_bf16(a, bf, acc[t], 0, 0, 0);
            }
        }
    }
    float cp5[5];
#pragma unroll
    for (int p = 0; p < 5; p++) cp5[p] = cp[b * NP + p];
#pragma unroll
    for (int t = 0; t < 8; t++) {
        int col = t * 16 + lm;
        float pt = c1[col];
#pragma unroll
        for (int p = 0; p < 5; p++) pt += cp5[p] * U1[(256 + p) * 128 + col];
#pragma unroll
        for (int r = 0; r < 4; r++) {
            int nd = block0 + w * 16 + lq * 4 + r;
            hid[(size_t)nd * 128 + col] = f2b(swishf(acc[t][r] + pt));
        }
    }
}

// ---------------- update stage 2: f += swish(hid@U2 + c2) (MFMA) ----------------
__global__ __launch_bounds__(256) void upd2_mfma(
    const unsigned short* __restrict__ hid,
    const unsigned short* __restrict__ u2T,
    const float* __restrict__ c2,
    float* __restrict__ f)
{
    __shared__ unsigned short lA[64 * LDK];
    __shared__ unsigned short lB[128 * LDK];
    int tid = threadIdx.x;
    int block0 = blockIdx.x * 64;
    {
        int r = tid >> 2, p4 = tid & 3;
        const unsigned short* src = hid + (size_t)(block0 + r) * 128 + p4 * 32;
        unsigned short* dst = lA + r * LDK + p4 * 32;
#pragma unroll
        for (int j = 0; j < 4; j++)
            *(short8*)(dst + j * 8) = *(const short8*)(src + j * 8);
    }
    {
        int r = tid >> 1, p4 = tid & 1;
        const unsigned short* src = u2T + r * 128 + p4 * 64;
        unsigned short* dst = lB + r * LDK + p4 * 64;
#pragma unroll
        for (int j = 0; j < 8; j++)
            *(short8*)(dst + j * 8) = *(const short8*)(src + j * 8);
    }
    __syncthreads();
    int w = tid >> 6, lane = tid & 63;
    int lm = lane & 15, lq = lane >> 4;
    floatx4 acc[8];
#pragma unroll
    for (int t = 0; t < 8; t++) acc[t] = (floatx4)(0.f);
#pragma unroll
    for (int ks = 0; ks < 4; ks++) {
        short8 a = *(const short8*)(lA + (w * 16 + lm) * LDK + ks * 32 + lq * 8);
#pragma unroll
        for (int t = 0; t < 8; t++) {
            short8 bf = *(const short8*)(lB + (t * 16 + lm) * LDK + ks * 32 + lq * 8);
            acc[t] = __builtin_amdgcn_mfma_f32_16x16x32_bf16(a, bf, acc[t], 0, 0, 0);
        }
    }
#pragma unroll
    for (int t = 0; t < 8; t++) {
        int col = t * 16 + lm;
        float cc = c2[col];
#pragma unroll
        for (int r = 0; r < 4; r++) {
            int nd = block0 + w * 16 + lq * 4 + r;
            size_t o = (size_t)nd * 128 + col;
            f[o] = f[o] + swishf(acc[t][r] + cc);
        }
    }
}

// ---------------- per-batch channel stats ----------------
__global__ __launch_bounds__(256) void stats_kernel(
    const float* __restrict__ f, float* __restrict__ stats)
{
    __shared__ float redA[256], redB[256];
    int blk = blockIdx.x;
    int b = blk >> 6;
    int slice = blk & 63;
    int base = b * NBAT + slice * 256;
    int tid = threadIdx.x;
    int ch = tid & 127, half = tid >> 7;
    float s = 0.f, s2 = 0.f;
    for (int rr = half; rr < 256; rr += 2) {
        float v = f[(size_t)(base + rr) * 128 + ch];
        s += v; s2 += v * v;
    }
    redA[tid] = s; redB[tid] = s2;
    __syncthreads();
    if (tid < 128) {
        s = redA[tid] + redA[tid + 128];
        s2 = redB[tid] + redB[tid + 128];
        atomicAdd(&stats[b * 256 + tid], s);
        atomicAdd(&stats[b * 256 + 128 + tid], s2);
    }
}

// ---------------- apply norm; emit fp32 + bf16 ----------------
__global__ __launch_bounds__(256) void norm_apply(
    const float* __restrict__ stats, float* __restrict__ f,
    unsigned short* __restrict__ fbf)
{
    int idx = blockIdx.x * 256 + threadIdx.x;
    int ch = idx & 127;
    int n = idx >> 7;
    int b = n >> 14;
    float mean = stats[b * 256 + ch] * (1.f / 16384.f);
    float ex2  = stats[b * 256 + 128 + ch] * (1.f / 16384.f);
    float var = ex2 - mean * mean;
    float v = (f[idx] - mean) * rsqrtf(var + EPS);
    f[idx] = v;
    fbf[idx] = f2b(v);
}

// ---------------- output head ----------------
__global__ __launch_bounds__(256) void out_head(
    const float* __restrict__ f, const float* __restrict__ u,
    const float* __restrict__ O1, const float* __restrict__ ob1,
    const float* __restrict__ O2, const float* __restrict__ ob2,
    float* __restrict__ out)
{
    __shared__ float fr[4][128];
    int tid = threadIdx.x;
    int w = tid >> 6, lane = tid & 63;
    int n = blockIdx.x * 4 + w;
    fr[w][lane] = f[(size_t)n * 128 + lane];
    fr[w][64 + lane] = f[(size_t)n * 128 + 64 + lane];
    __syncthreads();
    float acc = ob1[lane];
#pragma unroll 4
    for (int k = 0; k < 128; k++) acc += fr[w][k] * O1[k * 64 + lane];
    float v = swishf(acc) * O2[lane];
#pragma unroll
    for (int off = 32; off > 0; off >>= 1) v += __shfl_down(v, off);
    if (lane == 0) out[n] = u[n] + DT * (v + ob2[0]);
}

extern "C" void kernel_launch(void* const* d_in, const int* in_sizes, int n_in,
                              void* d_out, int out_size, void* d_ws, size_t ws_size,
                              hipStream_t stream)
{
    const float* inputs = (const float*)d_in[0];
    const float* cp     = (const float*)d_in[1];
    const float* emb_W1 = (const float*)d_in[3];
    const float* emb_b1 = (const float*)d_in[4];
    const float* emb_W2 = (const float*)d_in[5];
    const float* emb_b2 = (const float*)d_in[6];
    const float* msg1_W = (const float*)d_in[7];
    const float* msg1_b = (const float*)d_in[8];
    const float* msg2_W = (const float*)d_in[9];
    const float* msg2_b = (const float*)d_in[10];
    const float* upd1_W = (const float*)d_in[11];
    const float* upd1_b = (const float*)d_in[12];
    const float* upd2_W = (const float*)d_in[13];
    const float* upd2_b = (const float*)d_in[14];
    const float* out_W1 = (const float*)d_in[15];
    const float* out_b1 = (const float*)d_in[16];
    const float* out_W2 = (const float*)d_in[17];
    const float* out_b2 = (const float*)d_in[18];
    float* out = (float*)d_out;

    char* base = (char*)d_ws;
    size_t off = 0;
    float* f = (float*)(base + off);            off += (size_t)NNODE * 128 * 4;
    unsigned short* fbf  = (unsigned short*)(base + off); off += (size_t)NNODE * 128 * 2;
    unsigned short* Pn   = (unsigned short*)(base + off); off += (size_t)NNODE * 128 * 2;
    unsigned short* Qn   = (unsigned short*)(base + off); off += (size_t)NNODE * 128 * 2;
    unsigned short* aggb = (unsigned short*)(base + off); off += (size_t)NNODE * 128 * 2;
    unsigned short* hid  = (unsigned short*)(base + off); off += (size_t)NNODE * 128 * 2;
    float* u    = (float*)(base + off); off += NNODE * 4;
    float* posx = (float*)(base + off); off += NNODE * 4;
    float* posy = (float*)(base + off); off += NNODE * 4;
    float* stats = (float*)(base + off); off += 1024 * 4;
    unsigned short* wPT = (unsigned short*)(base + off); off += 6 * 16384 * 2;
    unsigned short* wQT = (unsigned short*)(base + off); off += 6 * 16384 * 2;
    unsigned short* w2T = (unsigned short*)(base + off); off += 6 * 16384 * 2;
    unsigned short* u1T = (unsigned short*)(base + off); off += 6 * 32768 * 2;
    unsigned short* u2T = (unsigned short*)(base + off); off += 6 * 16384 * 2;

    // weight prep (once per launch)
    prep_w<<<(6 * 16384 + 255) / 256, 256, 0, stream>>>(msg1_W, wPT, 264, 0,   128, 6 * 16384);
    prep_w<<<(6 * 16384 + 255) / 256, 256, 0, stream>>>(msg1_W, wQT, 264, 128, 128, 6 * 16384);
    prep_w<<<(6 * 16384 + 255) / 256, 256, 0, stream>>>(msg2_W, w2T, 128, 0,   128, 6 * 16384);
    prep_w<<<(6 * 32768 + 255) / 256, 256, 0, stream>>>(upd1_W, u1T, 261, 0,   256, 6 * 32768);
    prep_w<<<(6 * 16384 + 255) / 256, 256, 0, stream>>>(upd2_W, u2T, 128, 0,   128, 6 * 16384);

    node_init<<<256, 256, 0, stream>>>(inputs, cp, u, posx, posy);
    embed_kernel<<<32768, 256, 0, stream>>>(u, posx, posy, cp,
                                            emb_W1, emb_b1, emb_W2, emb_b2, f, fbf);
    for (int l = 0; l < 6; l++) {
        pq_mfma<<<1024, 256, 0, stream>>>(fbf,
                                          wPT + (size_t)l * 16384,
                                          wQT + (size_t)l * 16384,
                                          msg1_W + (size_t)l * 264 * 128,
                                          msg1_b + (size_t)l * 128,
                                          u, posx, posy, cp, Pn, Qn);
        msg_mfma<<<8192, 256, 0, stream>>>(Pn, Qn,
                                           w2T + (size_t)l * 16384,
                                           msg2_b + (size_t)l * 128, aggb);
        upd1_mfma<<<1024, 256, 0, stream>>>(fbf, aggb,
                                            u1T + (size_t)l * 32768,
                                            upd1_W + (size_t)l * 261 * 128,
                                            upd1_b + (size_t)l * 128, cp, hid);
        upd2_mfma<<<1024, 256, 0, stream>>>(hid,
                                            u2T + (size_t)l * 16384,
                                            upd2_b + (size_t)l * 128, f);
        hipMemsetAsync(stats, 0, 1024 * sizeof(float), stream);
        stats_kernel<<<256, 256, 0, stream>>>(f, stats);
        norm_apply<<<32768, 256, 0, stream>>>(stats, f, fbf);
    }
    out_head<<<16384, 256, 0, stream>>>(f, u, out_W1, out_b1, out_W2, out_b2, out);
}